// Round 4
// baseline (437.003 us; speedup 1.0000x reference)
//
#include <hip/hip_runtime.h>
#include <hip/hip_bf16.h>

typedef __attribute__((ext_vector_type(8))) short bf16x8;
typedef __attribute__((ext_vector_type(4))) float f32x4;
typedef unsigned short u16;
typedef unsigned int u32;

#define MFMA16(a,b,c) __builtin_amdgcn_mfma_f32_16x16x32_bf16((a),(b),(c),0,0,0)

#if defined(__has_builtin) && __has_builtin(__builtin_amdgcn_exp2f)
#define EXP2(x) __builtin_amdgcn_exp2f(x)
#else
#define EXP2(x) exp2f(x)
#endif

// softmax scale folded into Q at projection time: (1/32) * log2(e)
#define QSCALE 0.045084220027780106f

__device__ __forceinline__ u16 f2bf(float f) {
  union { float f; unsigned int u; } v; v.f = f;
  unsigned int r = v.u + 0x7FFFu + ((v.u >> 16) & 1u);   // RNE
  return (u16)(r >> 16);
}

__device__ __forceinline__ u32 pkbf(float a, float b) {
  union { __hip_bfloat162 h; u32 u; } cv;
  cv.h = __float22bfloat162_rn(make_float2(a, b));
  return cv.u;
}

// async global->LDS, 16B per lane; LDS dest = wave-uniform base + lane*16
__device__ __forceinline__ void gld16(const void* g, void* l) {
  __builtin_amdgcn_global_load_lds(
      (__attribute__((address_space(1))) void*)(g),
      (__attribute__((address_space(3))) void*)(l), 16, 0, 0);
}

// ---------------- cast fp32 -> bf16 (all inputs, one launch) ----------------
__global__ __launch_bounds__(256) void cast_all(
    const float* __restrict__ x, const float* __restrict__ qu,
    const float* __restrict__ wq, const float* __restrict__ wk,
    const float* __restrict__ wv, const float* __restrict__ wo,
    u16* __restrict__ xb, u16* __restrict__ qub,
    u16* __restrict__ wqb, u16* __restrict__ wkb,
    u16* __restrict__ wvb, u16* __restrict__ wob)
{
  int i = blockIdx.x * 256 + threadIdx.x;   // float4 index
  const float4* src; u16* dst; int off;
  if (i < 1048576)      { src = (const float4*)qu; dst = qub; off = i; }
  else if (i < 2097152) { src = (const float4*)x;  dst = xb;  off = i - 1048576; }
  else if (i < 2359296) { src = (const float4*)wq; dst = wqb; off = i - 2097152; }
  else if (i < 2621440) { src = (const float4*)wk; dst = wkb; off = i - 2359296; }
  else if (i < 2883584) { src = (const float4*)wv; dst = wvb; off = i - 2621440; }
  else                  { src = (const float4*)wo; dst = wob; off = i - 2883584; }
  float4 v = src[off];
  ushort4 r; r.x = f2bf(v.x); r.y = f2bf(v.y); r.z = f2bf(v.z); r.w = f2bf(v.w);
  ((ushort4*)dst)[off] = r;
}

// ---------------- fused QKV projection GEMM ----------------
// z=0: Q*(scale*log2e) -> [B,H,N,D]; z=1: K -> [B,H,N,D]  — computed as C^T
//      (swap MFMA operands) so each lane holds 4 consecutive channels ->
//      packed 8-B stores, no LDS transpose.
// z=2: V -> [B,H,D,N'] — normal orientation: lane j-values are 4 consecutive
//      permuted tokens (k' = (mt&2)*16 + quad*8 + (mt&1)*4 + j) -> packed
//      8-B stores directly into the transposed layout.
__global__ __launch_bounds__(256) void gemm_qkv(
    const u16* __restrict__ qub, const u16* __restrict__ xb,
    const u16* __restrict__ wqb, const u16* __restrict__ wkb, const u16* __restrict__ wvb,
    const float* __restrict__ bq, const float* __restrict__ bk, const float* __restrict__ bv,
    u16* __restrict__ qhd, u16* __restrict__ khd, u16* __restrict__ vtd)
{
  __shared__ u16 As[128 * 64];
  __shared__ u16 Bs[128 * 64];
  int tid = threadIdx.x, w = tid >> 6, lane = tid & 63;
  int c = lane & 15, quad = lane >> 4;
  int bm = blockIdx.x, bn = blockIdx.y, z = blockIdx.z;
  int wm = w >> 1, wn = w & 1;
  const u16* A = (z == 0) ? qub : xb;
  const u16* W = (z == 0) ? wqb : (z == 1) ? wkb : wvb;
  f32x4 acc[4][4] = {};
  for (int k0 = 0; k0 < 1024; k0 += 64) {
#pragma unroll
    for (int i = 0; i < 4; i++) {
      int seg = i * 256 + w * 64 + lane;          // physical 8-elem segment
      int row = seg >> 3, pseg = seg & 7;
      int lseg = pseg ^ (row & 7);                // logical k-segment (XOR swizzle)
      gld16(A + (size_t)(bm * 128 + row) * 1024 + k0 + lseg * 8,
            &As[(i * 256 + w * 64) * 8]);
      gld16(W + (size_t)(bn * 128 + row) * 1024 + k0 + lseg * 8,
            &Bs[(i * 256 + w * 64) * 8]);
    }
    __syncthreads();
#pragma unroll
    for (int ks = 0; ks < 2; ks++) {
      bf16x8 af[4], bfr[4];
#pragma unroll
      for (int mt = 0; mt < 4; mt++) {
        int row = wm * 64 + mt * 16 + c;
        int cseg = (ks * 4 + quad) ^ (row & 7);
        af[mt] = *(const bf16x8*)&As[(row * 8 + cseg) * 8];
      }
#pragma unroll
      for (int nt = 0; nt < 4; nt++) {
        int row = wn * 64 + nt * 16 + c;
        int cseg = (ks * 4 + quad) ^ (row & 7);
        bfr[nt] = *(const bf16x8*)&Bs[(row * 8 + cseg) * 8];
      }
      if (z < 2) {
        // C^T: rows = channels (W frags as A-operand), cols = tokens
#pragma unroll
        for (int ct = 0; ct < 4; ct++)
#pragma unroll
          for (int tt = 0; tt < 4; tt++)
            acc[ct][tt] = MFMA16(bfr[ct], af[tt], acc[ct][tt]);
      } else {
#pragma unroll
        for (int mt = 0; mt < 4; mt++)
#pragma unroll
          for (int nt = 0; nt < 4; nt++)
            acc[mt][nt] = MFMA16(af[mt], bfr[nt], acc[mt][nt]);
      }
    }
    __syncthreads();
  }
  if (z < 2) {
    const float* bias = (z == 0) ? bq : bk;
    u16* dst = (z == 0) ? qhd : khd;
    float sc = (z == 0) ? QSCALE : 1.0f;
    // per-lane bias for 4 consecutive channels per ct (16B-aligned)
    float4 bbs[4];
#pragma unroll
    for (int ct = 0; ct < 4; ct++) {
      float4 b4 = *(const float4*)&bias[bn * 128 + wn * 64 + ct * 16 + quad * 4];
      bbs[ct].x = b4.x * sc; bbs[ct].y = b4.y * sc;
      bbs[ct].z = b4.z * sc; bbs[ct].w = b4.w * sc;
    }
#pragma unroll
    for (int ct = 0; ct < 4; ct++) {
      int ch = bn * 128 + wn * 64 + ct * 16 + quad * 4;
      int h = ch >> 6, d0 = ch & 63;
#pragma unroll
      for (int tt = 0; tt < 4; tt++) {
        int tok = bm * 128 + wm * 64 + tt * 16 + c;
        int b = tok >> 11, n = tok & 2047;
        float v0 = fmaf(acc[ct][tt][0], sc, bbs[ct].x);
        float v1 = fmaf(acc[ct][tt][1], sc, bbs[ct].y);
        float v2 = fmaf(acc[ct][tt][2], sc, bbs[ct].z);
        float v3 = fmaf(acc[ct][tt][3], sc, bbs[ct].w);
        uint2 pk; pk.x = pkbf(v0, v1); pk.y = pkbf(v2, v3);
        *(uint2*)&dst[((size_t)(b * 16 + h) * 2048 + n) * 64 + d0] = pk;
      }
    }
  } else {
    float bval[4];
#pragma unroll
    for (int nt = 0; nt < 4; nt++)
      bval[nt] = bv[bn * 128 + wn * 64 + nt * 16 + c];
#pragma unroll
    for (int mt = 0; mt < 4; mt++) {
      int tokl = (mt & 2) * 16 + quad * 8 + (mt & 1) * 4;   // permuted, +j
      int tok = bm * 128 + wm * 64 + tokl;
      int b = tok >> 11, np = tok & 2047;
#pragma unroll
      for (int nt = 0; nt < 4; nt++) {
        int ch = bn * 128 + wn * 64 + nt * 16 + c;
        int h = ch >> 6, d = ch & 63;
        float v0 = acc[mt][nt][0] + bval[nt];
        float v1 = acc[mt][nt][1] + bval[nt];
        float v2 = acc[mt][nt][2] + bval[nt];
        float v3 = acc[mt][nt][3] + bval[nt];
        uint2 pk; pk.x = pkbf(v0, v1); pk.y = pkbf(v2, v3);
        *(uint2*)&vtd[((size_t)(b * 16 + h) * 64 + d) * 2048 + np] = pk;
      }
    }
  }
}

// ---------------- attention v9: independent waves, epilogue LDS combine ----
// grid (32 bh, 64 qt), block = 128 thr (2 waves). Both waves own the SAME
// 32-q tile; wave w sweeps tokens [w*1024, w*1024+1024) in 32 tiles of 32.
// No barriers in the sweep; partial O/L combined in LDS at the epilogue.
// T14 staging: global->reg prefetch of tile t+1 issued before compute of t,
// reg->LDS into a SINGLE 8 KB buffer per wave (16.2 KB/block -> 8 blocks/CU
// -> 16 waves/CU). Compiler-inserted per-wave waitcnts only (no drains).
__global__ __launch_bounds__(128, 4) void attn(
    const u16* __restrict__ qh, const u16* __restrict__ kh,
    const u16* __restrict__ vt, u16* __restrict__ ot)
{
  __shared__ u16 KL[2][32 * 64];   // per-wave K tile [32 tok][64 d], swizzled
  __shared__ u16 VL[2][64 * 32];   // per-wave V tile [64 d][32 tok'], swizzled
  __shared__ float CL[32];         // wave-1 L partials
  int tid = threadIdx.x, w = tid >> 6, lane = tid & 63;
  int c = lane & 15, quad = lane >> 4;
  int bh = blockIdx.x, qt = blockIdx.y;

  // Q B-frags in registers (shared q-tile: both waves load the same 32 q)
  const u16* qp = qh + ((size_t)bh * 2048 + qt * 32) * 64;
  bf16x8 Qf[2][2];
#pragma unroll
  for (int qt2 = 0; qt2 < 2; qt2++)
#pragma unroll
    for (int ks = 0; ks < 2; ks++)
      Qf[qt2][ks] = *(const bf16x8*)(qp + (size_t)(qt2 * 16 + c) * 64 + ks * 32 + quad * 8);

  // staging lane geometry
  // K: 4 loads; load i covers token-row i*8+(lane>>3), seg (lane&7)^(row&7)
  int kro = (lane >> 3);
  int ksw = ((lane & 7) ^ (kro & 7)) * 8;
  const u16* kg = kh + (size_t)bh * 131072 + (size_t)w * 65536 + kro * 64 + ksw;
  int kwo = (kro * 64 + (lane & 7) * 8);            // linear LDS dest (elems)
  // V: 4 loads; load i covers d-row i*16+(lane>>2), seg (lane&3)^(row&3)
  int vro = (lane >> 2);
  int vsw = ((lane & 3) ^ (vro & 3)) * 8;
  const u16* vg = vt + (size_t)bh * 131072 + (size_t)vro * 2048 + w * 1024 + vsw;
  int vwo = (vro * 32 + (lane & 3) * 8);

  u16* Ks = KL[w];
  u16* Vs = VL[w];

  // fragment read offsets (swizzled; row&7 == c&7 for K, row&3 == c&3 for V)
  int offK[2][2], offV[4];
#pragma unroll
  for (int nt = 0; nt < 2; nt++)
#pragma unroll
    for (int ks = 0; ks < 2; ks++)
      offK[nt][ks] = (nt * 16 + c) * 64 + (((ks * 4 + quad) ^ (c & 7)) & 7) * 8;
#pragma unroll
  for (int dt = 0; dt < 4; dt++)
    offV[dt] = (dt * 16 + c) * 32 + ((quad ^ (c & 3)) & 3) * 8;

  uint4 RK[4], RV[4];
#define ISSUE(T)                                                                \
  {                                                                             \
    const u16* kp = kg + (T) * 2048;                                            \
    const u16* vp = vg + (T) * 32;                                              \
    RK[0] = *(const uint4*)(kp);                                                \
    RK[1] = *(const uint4*)(kp + 512);                                          \
    RK[2] = *(const uint4*)(kp + 1024);                                         \
    RK[3] = *(const uint4*)(kp + 1536);                                         \
    RV[0] = *(const uint4*)(vp);                                                \
    RV[1] = *(const uint4*)(vp + 32768);                                        \
    RV[2] = *(const uint4*)(vp + 65536);                                        \
    RV[3] = *(const uint4*)(vp + 98304);                                        \
  }

  f32x4 O[2][4] = {};
  f32x4 Lacc[2] = {};
  bf16x8 vone;
#pragma unroll
  for (int j = 0; j < 8; j++) vone[j] = (short)0x3F80;   // bf16 1.0

  ISSUE(0)

  for (int t = 0; t < 32; t++) {
    // write staged tile t into LDS (waits vmcnt for RK/RV automatically)
#pragma unroll
    for (int i = 0; i < 4; i++) {
      *(uint4*)&Ks[i * 512 + kwo] = RK[i];
      *(uint4*)&Vs[i * 512 + vwo] = RV[i];
    }
    // issue prefetch of tile t+1 (pin issue point before compute)
    if (t < 31) ISSUE(t + 1)
    __builtin_amdgcn_sched_barrier(0);

    // K frags + S = K·Q^T (S^T trick: lane c = q-col)
    bf16x8 Kf[2][2];
#pragma unroll
    for (int nt = 0; nt < 2; nt++) {
      Kf[nt][0] = *(const bf16x8*)&Ks[offK[nt][0]];
      Kf[nt][1] = *(const bf16x8*)&Ks[offK[nt][1]];
    }
    f32x4 S[2][2] = {};
#pragma unroll
    for (int qt2 = 0; qt2 < 2; qt2++)
#pragma unroll
      for (int nt = 0; nt < 2; nt++) {
        S[qt2][nt] = MFMA16(Kf[nt][0], Qf[qt2][0], S[qt2][nt]);
        S[qt2][nt] = MFMA16(Kf[nt][1], Qf[qt2][1], S[qt2][nt]);
      }
    // P = exp2(S) packed: pa[qt2] = [S0 j0..3 | S1 j0..3] -> k-slots match V'
    bf16x8 pa[2];
#pragma unroll
    for (int qt2 = 0; qt2 < 2; qt2++) {
      float e0 = EXP2(S[qt2][0][0]), e1 = EXP2(S[qt2][0][1]);
      float e2 = EXP2(S[qt2][0][2]), e3 = EXP2(S[qt2][0][3]);
      float e4 = EXP2(S[qt2][1][0]), e5 = EXP2(S[qt2][1][1]);
      float e6 = EXP2(S[qt2][1][2]), e7 = EXP2(S[qt2][1][3]);
      union { uint4 u; bf16x8 v; } cv;
      cv.u.x = pkbf(e0, e1); cv.u.y = pkbf(e2, e3);
      cv.u.z = pkbf(e4, e5); cv.u.w = pkbf(e6, e7);
      pa[qt2] = cv.v;
    }
    Lacc[0] = MFMA16(pa[0], vone, Lacc[0]);
    Lacc[1] = MFMA16(pa[1], vone, Lacc[1]);
    // V frags + PV
    bf16x8 Vf[4];
#pragma unroll
    for (int dt = 0; dt < 4; dt++)
      Vf[dt] = *(const bf16x8*)&Vs[offV[dt]];
#pragma unroll
    for (int qt2 = 0; qt2 < 2; qt2++)
#pragma unroll
      for (int dt = 0; dt < 4; dt++)
        O[qt2][dt] = MFMA16(pa[qt2], Vf[dt], O[qt2][dt]);
  }
#undef ISSUE

  // ---- epilogue: combine the two waves' partials through LDS ----
  __syncthreads();
  float* CmbO = (float*)&VL[0][0];   // 8 KB: [32 q][64 d] f32 (wave-1 partial)
  if (w == 1) {
#pragma unroll
    for (int qt2 = 0; qt2 < 2; qt2++) {
      if (c == 0)
        *(f32x4*)&CL[qt2 * 16 + quad * 4] = Lacc[qt2];
#pragma unroll
      for (int dt = 0; dt < 4; dt++)
#pragma unroll
        for (int j = 0; j < 4; j++)
          CmbO[(qt2 * 16 + quad * 4 + j) * 64 + dt * 16 + c] = O[qt2][dt][j];
    }
  }
  __syncthreads();
  if (w == 0) {
    int b_ = bh >> 4, h = bh & 15;
#pragma unroll
    for (int qt2 = 0; qt2 < 2; qt2++) {
#pragma unroll
      for (int j = 0; j < 4; j++) {
        int qrow = qt2 * 16 + quad * 4 + j;
        float ltot = Lacc[qt2][j] + CL[qrow];
        float linv = 1.0f / ltot;
        int n = qt * 32 + qrow;
        u16* op = ot + (((size_t)b_ * 2048 + n) * 16 + h) * 64;
#pragma unroll
        for (int dt = 0; dt < 4; dt++) {
          float o = O[qt2][dt][j] + CmbO[qrow * 64 + dt * 16 + c];
          op[dt * 16 + c] = f2bf(o * linv);
        }
      }
    }
  }
}

// ---------------- output projection GEMM (fp32 out), 64x128 tile ----------
__global__ __launch_bounds__(256) void gemm_out(
    const u16* __restrict__ Aot, const u16* __restrict__ wob,
    const float* __restrict__ bo, float* __restrict__ out)
{
  __shared__ u16 As[64 * 64];
  __shared__ u16 Bs[128 * 64];
  int tid = threadIdx.x, w = tid >> 6, lane = tid & 63;
  int bm = blockIdx.x, bn = blockIdx.y;
  int wm = w >> 1, wn = w & 1;
  f32x4 acc[2][4] = {};
  for (int k0 = 0; k0 < 1024; k0 += 64) {
#pragma unroll
    for (int i = 0; i < 2; i++) {
      int seg = i * 256 + tid;
      int row = seg >> 3, pseg = seg & 7;
      int lseg = pseg ^ (row & 7);
      gld16(Aot + (size_t)(bm * 64 + row) * 1024 + k0 + lseg * 8,
            &As[(i * 256 + tid - (tid & 7)) * 8 + (tid & 7) * 8]);
    }
#pragma unroll
    for (int i = 0; i < 4; i++) {
      int seg = i * 256 + tid;
      int row = seg >> 3, pseg = seg & 7;
      int lseg = pseg ^ (row & 7);
      gld16(wob + (size_t)(bn * 128 + row) * 1024 + k0 + lseg * 8,
            &Bs[(i * 256 + tid - (tid & 7)) * 8 + (tid & 7) * 8]);
    }
    __syncthreads();
#pragma unroll
    for (int ks = 0; ks < 2; ks++) {
      bf16x8 af[2], bfr[4];
#pragma unroll
      for (int mt = 0; mt < 2; mt++) {
        int row = wm * 32 + mt * 16 + (lane & 15);
        int cseg = (ks * 4 + (lane >> 4)) ^ (row & 7);
        af[mt] = *(const bf16x8*)&As[(row * 8 + cseg) * 8];
      }
#pragma unroll
      for (int nt = 0; nt < 4; nt++) {
        int row = wn * 64 + nt * 16 + (lane & 15);
        int cseg = (ks * 4 + (lane >> 4)) ^ (row & 7);
        bfr[nt] = *(const bf16x8*)&Bs[(row * 8 + cseg) * 8];
      }
#pragma unroll
      for (int mt = 0; mt < 2; mt++)
#pragma unroll
        for (int nt = 0; nt < 4; nt++)
          acc[mt][nt] = MFMA16(af[mt], bfr[nt], acc[mt][nt]);
    }
    __syncthreads();
  }
#pragma unroll
  for (int nt = 0; nt < 4; nt++) {
    int o = bn * 128 + wn * 64 + nt * 16 + (lane & 15);
    float bval = bo[o];
#pragma unroll
    for (int mt = 0; mt < 2; mt++)
#pragma unroll
      for (int j = 0; j < 4; j++) {
        int m = bm * 64 + wm * 32 + mt * 16 + (lane >> 4) * 4 + j;
        out[(size_t)m * 1024 + o] = acc[mt][nt][j] + bval;
      }
  }
}

extern "C" void kernel_launch(void* const* d_in, const int* in_sizes, int n_in,
                              void* d_out, int out_size, void* d_ws, size_t ws_size,
                              hipStream_t stream)
{
  const float* x  = (const float*)d_in[0];
  const float* qu = (const float*)d_in[1];
  const float* wq = (const float*)d_in[2];
  const float* bq = (const float*)d_in[3];
  const float* wk = (const float*)d_in[4];
  const float* bk = (const float*)d_in[5];
  const float* wv = (const float*)d_in[6];
  const float* bv = (const float*)d_in[7];
  const float* wo = (const float*)d_in[8];
  const float* bo = (const float*)d_in[9];
  float* out = (float*)d_out;
  char* ws = (char*)d_ws;
  u16* xb  = (u16*)(ws + (size_t)0);          // 8 MB
  u16* qub = (u16*)(ws + ((size_t)8  << 20)); // 8 MB
  u16* wqb = (u16*)(ws + ((size_t)16 << 20)); // 2 MB
  u16* wkb = (u16*)(ws + ((size_t)18 << 20)); // 2 MB
  u16* wvb = (u16*)(ws + ((size_t)20 << 20)); // 2 MB
  u16* wob = (u16*)(ws + ((size_t)22 << 20)); // 2 MB
  u16* qhd = (u16*)(ws + ((size_t)24 << 20)); // 8 MB  Q-scaled [B,H,N,D]
  u16* khd = (u16*)(ws + ((size_t)32 << 20)); // 8 MB  K [B,H,N,D]
  u16* vtd = (u16*)(ws + ((size_t)40 << 20)); // 8 MB  V^T permuted [B,H,D,N']
  u16* otd = (u16*)(ws + ((size_t)48 << 20)); // 8 MB  attn out [B,N,H,D]

  cast_all<<<12288, 256, 0, stream>>>(x, qu, wq, wk, wv, wo,
                                      xb, qub, wqb, wkb, wvb, wob);
  gemm_qkv<<<dim3(32, 8, 3), 256, 0, stream>>>(qub, xb, wqb, wkb, wvb,
                                               bq, bk, bv, qhd, khd, vtd);
  attn<<<dim3(32, 64), 128, 0, stream>>>(qhd, khd, vtd, otd);
  gemm_out<<<dim3(64, 8), 256, 0, stream>>>(otd, wob, bo, out);
}

// Round 5
// 275.451 us; speedup vs baseline: 1.5865x; 1.5865x over previous
//
#include <hip/hip_runtime.h>
#include <hip/hip_bf16.h>

typedef __attribute__((ext_vector_type(8))) short bf16x8;
typedef __attribute__((ext_vector_type(4))) float f32x4;
typedef unsigned short u16;
typedef unsigned int u32;

#define MFMA16(a,b,c) __builtin_amdgcn_mfma_f32_16x16x32_bf16((a),(b),(c),0,0,0)

#if defined(__has_builtin) && __has_builtin(__builtin_amdgcn_exp2f)
#define EXP2(x) __builtin_amdgcn_exp2f(x)
#else
#define EXP2(x) exp2f(x)
#endif

// softmax scale folded into Q at projection time: (1/32) * log2(e)
#define QSCALE 0.045084220027780106f

__device__ __forceinline__ u16 f2bf(float f) {
  union { float f; unsigned int u; } v; v.f = f;
  unsigned int r = v.u + 0x7FFFu + ((v.u >> 16) & 1u);   // RNE
  return (u16)(r >> 16);
}

__device__ __forceinline__ u32 pkbf(float a, float b) {
  union { __hip_bfloat162 h; u32 u; } cv;
  cv.h = __float22bfloat162_rn(make_float2(a, b));
  return cv.u;
}

// async global->LDS, 16B per lane; LDS dest = wave-uniform base + lane*16
__device__ __forceinline__ void gld16(const void* g, void* l) {
  __builtin_amdgcn_global_load_lds(
      (__attribute__((address_space(1))) void*)(g),
      (__attribute__((address_space(3))) void*)(l), 16, 0, 0);
}

// ---------------- cast fp32 -> bf16 (all inputs, one launch) ----------------
__global__ __launch_bounds__(256) void cast_all(
    const float* __restrict__ x, const float* __restrict__ qu,
    const float* __restrict__ wq, const float* __restrict__ wk,
    const float* __restrict__ wv, const float* __restrict__ wo,
    u16* __restrict__ xb, u16* __restrict__ qub,
    u16* __restrict__ wqb, u16* __restrict__ wkb,
    u16* __restrict__ wvb, u16* __restrict__ wob)
{
  int i = blockIdx.x * 256 + threadIdx.x;   // float4 index
  const float4* src; u16* dst; int off;
  if (i < 1048576)      { src = (const float4*)qu; dst = qub; off = i; }
  else if (i < 2097152) { src = (const float4*)x;  dst = xb;  off = i - 1048576; }
  else if (i < 2359296) { src = (const float4*)wq; dst = wqb; off = i - 2097152; }
  else if (i < 2621440) { src = (const float4*)wk; dst = wkb; off = i - 2359296; }
  else if (i < 2883584) { src = (const float4*)wv; dst = wvb; off = i - 2621440; }
  else                  { src = (const float4*)wo; dst = wob; off = i - 2883584; }
  float4 v = src[off];
  ushort4 r; r.x = f2bf(v.x); r.y = f2bf(v.y); r.z = f2bf(v.z); r.w = f2bf(v.w);
  ((ushort4*)dst)[off] = r;
}

// ---------------- fused QKV projection GEMM ----------------
// z=0: Q*(scale*log2e) -> [B,H,N,D]; z=1: K -> [B,H,N,D]  — computed as C^T
//      (swap MFMA operands) so each lane holds 4 consecutive channels ->
//      packed 8-B stores, no LDS transpose.
// z=2: V -> [B,H,D,N'] — normal orientation: lane j-values are 4 consecutive
//      permuted tokens (k' = (mt&2)*16 + quad*8 + (mt&1)*4 + j) -> packed
//      8-B stores directly into the transposed layout.
__global__ __launch_bounds__(256) void gemm_qkv(
    const u16* __restrict__ qub, const u16* __restrict__ xb,
    const u16* __restrict__ wqb, const u16* __restrict__ wkb, const u16* __restrict__ wvb,
    const float* __restrict__ bq, const float* __restrict__ bk, const float* __restrict__ bv,
    u16* __restrict__ qhd, u16* __restrict__ khd, u16* __restrict__ vtd)
{
  __shared__ u16 As[128 * 64];
  __shared__ u16 Bs[128 * 64];
  int tid = threadIdx.x, w = tid >> 6, lane = tid & 63;
  int c = lane & 15, quad = lane >> 4;
  int bm = blockIdx.x, bn = blockIdx.y, z = blockIdx.z;
  int wm = w >> 1, wn = w & 1;
  const u16* A = (z == 0) ? qub : xb;
  const u16* W = (z == 0) ? wqb : (z == 1) ? wkb : wvb;
  f32x4 acc[4][4] = {};
  for (int k0 = 0; k0 < 1024; k0 += 64) {
#pragma unroll
    for (int i = 0; i < 4; i++) {
      int seg = i * 256 + w * 64 + lane;          // physical 8-elem segment
      int row = seg >> 3, pseg = seg & 7;
      int lseg = pseg ^ (row & 7);                // logical k-segment (XOR swizzle)
      gld16(A + (size_t)(bm * 128 + row) * 1024 + k0 + lseg * 8,
            &As[(i * 256 + w * 64) * 8]);
      gld16(W + (size_t)(bn * 128 + row) * 1024 + k0 + lseg * 8,
            &Bs[(i * 256 + w * 64) * 8]);
    }
    __syncthreads();
#pragma unroll
    for (int ks = 0; ks < 2; ks++) {
      bf16x8 af[4], bfr[4];
#pragma unroll
      for (int mt = 0; mt < 4; mt++) {
        int row = wm * 64 + mt * 16 + c;
        int cseg = (ks * 4 + quad) ^ (row & 7);
        af[mt] = *(const bf16x8*)&As[(row * 8 + cseg) * 8];
      }
#pragma unroll
      for (int nt = 0; nt < 4; nt++) {
        int row = wn * 64 + nt * 16 + c;
        int cseg = (ks * 4 + quad) ^ (row & 7);
        bfr[nt] = *(const bf16x8*)&Bs[(row * 8 + cseg) * 8];
      }
      if (z < 2) {
        // C^T: rows = channels (W frags as A-operand), cols = tokens
#pragma unroll
        for (int ct = 0; ct < 4; ct++)
#pragma unroll
          for (int tt = 0; tt < 4; tt++)
            acc[ct][tt] = MFMA16(bfr[ct], af[tt], acc[ct][tt]);
      } else {
#pragma unroll
        for (int mt = 0; mt < 4; mt++)
#pragma unroll
          for (int nt = 0; nt < 4; nt++)
            acc[mt][nt] = MFMA16(af[mt], bfr[nt], acc[mt][nt]);
      }
    }
    __syncthreads();
  }
  if (z < 2) {
    const float* bias = (z == 0) ? bq : bk;
    u16* dst = (z == 0) ? qhd : khd;
    float sc = (z == 0) ? QSCALE : 1.0f;
    // per-lane bias for 4 consecutive channels per ct (16B-aligned)
    float4 bbs[4];
#pragma unroll
    for (int ct = 0; ct < 4; ct++) {
      float4 b4 = *(const float4*)&bias[bn * 128 + wn * 64 + ct * 16 + quad * 4];
      bbs[ct].x = b4.x * sc; bbs[ct].y = b4.y * sc;
      bbs[ct].z = b4.z * sc; bbs[ct].w = b4.w * sc;
    }
#pragma unroll
    for (int ct = 0; ct < 4; ct++) {
      int ch = bn * 128 + wn * 64 + ct * 16 + quad * 4;
      int h = ch >> 6, d0 = ch & 63;
#pragma unroll
      for (int tt = 0; tt < 4; tt++) {
        int tok = bm * 128 + wm * 64 + tt * 16 + c;
        int b = tok >> 11, n = tok & 2047;
        float v0 = fmaf(acc[ct][tt][0], sc, bbs[ct].x);
        float v1 = fmaf(acc[ct][tt][1], sc, bbs[ct].y);
        float v2 = fmaf(acc[ct][tt][2], sc, bbs[ct].z);
        float v3 = fmaf(acc[ct][tt][3], sc, bbs[ct].w);
        uint2 pk; pk.x = pkbf(v0, v1); pk.y = pkbf(v2, v3);
        *(uint2*)&dst[((size_t)(b * 16 + h) * 2048 + n) * 64 + d0] = pk;
      }
    }
  } else {
    float bval[4];
#pragma unroll
    for (int nt = 0; nt < 4; nt++)
      bval[nt] = bv[bn * 128 + wn * 64 + nt * 16 + c];
#pragma unroll
    for (int mt = 0; mt < 4; mt++) {
      int tokl = (mt & 2) * 16 + quad * 8 + (mt & 1) * 4;   // permuted, +j
      int tok = bm * 128 + wm * 64 + tokl;
      int b = tok >> 11, np = tok & 2047;
#pragma unroll
      for (int nt = 0; nt < 4; nt++) {
        int ch = bn * 128 + wn * 64 + nt * 16 + c;
        int h = ch >> 6, d = ch & 63;
        float v0 = acc[mt][nt][0] + bval[nt];
        float v1 = acc[mt][nt][1] + bval[nt];
        float v2 = acc[mt][nt][2] + bval[nt];
        float v3 = acc[mt][nt][3] + bval[nt];
        uint2 pk; pk.x = pkbf(v0, v1); pk.y = pkbf(v2, v3);
        *(uint2*)&vtd[((size_t)(b * 16 + h) * 64 + d) * 2048 + np] = pk;
      }
    }
  }
}

// ---------------- attention v10: no LDS staging, direct L2 fragment reads --
// grid (32 bh, 64 qt), block = 128 thr (2 waves). Both waves own the SAME
// 32-q tile; wave w sweeps tokens [w*1024, w*1024+1024) in 32 tiles of 32.
// K/V are L2-resident (2 MB per XCD with bh%8 affinity) -> MFMA fragments
// are read DIRECTLY from global as 16 B/lane dwordx4 (16 full 64-B lines
// per load). No LDS, no barriers, no waitcnt asm in the sweep. Partials
// combined in LDS at the epilogue (one barrier). No forced low VGPR bound
// (v9's (128,4) caused a reg-staging spill: VGPR=56, 1 GB scratch traffic).
__global__ __launch_bounds__(128, 3) void attn(
    const u16* __restrict__ qh, const u16* __restrict__ kh,
    const u16* __restrict__ vt, u16* __restrict__ ot)
{
  __shared__ float CmbO[32 * 64];   // 8 KB wave-1 partial O
  __shared__ float CL[32];          // wave-1 partial L
  int tid = threadIdx.x, w = tid >> 6, lane = tid & 63;
  int c = lane & 15, quad = lane >> 4;
  int bh = blockIdx.x, qt = blockIdx.y;

  // Q B-frags in registers: B[k=d][n=q], lane c = q-col
  const u16* qp = qh + ((size_t)bh * 2048 + qt * 32) * 64;
  bf16x8 Qf[2][2];
#pragma unroll
  for (int q2 = 0; q2 < 2; q2++)
#pragma unroll
    for (int ks = 0; ks < 2; ks++)
      Qf[q2][ks] = *(const bf16x8*)(qp + (size_t)(q2 * 16 + c) * 64 + ks * 32 + quad * 8);

  // K frag base: token = w*1024 + t*32 + nt*16 + c, elem = ks*32 + quad*8
  const u16* kb = kh + (size_t)bh * 131072 + (size_t)(w * 1024 + c) * 64 + quad * 8;
  // V frag base: d-row = dt*16 + c, tok' = w*1024 + t*32 + quad*8 (+j)
  const u16* vb = vt + (size_t)bh * 131072 + (size_t)c * 2048 + w * 1024 + quad * 8;

  f32x4 O[2][4] = {};
  f32x4 Lacc[2] = {};
  bf16x8 vone;
#pragma unroll
  for (int j = 0; j < 8; j++) vone[j] = (short)0x3F80;   // bf16 1.0

  for (int t = 0; t < 32; t++) {
    const u16* kt = kb + t * 2048;
    const u16* vp = vb + t * 32;
    bf16x8 Kf00 = *(const bf16x8*)(kt);              // nt=0, d 0..31
    bf16x8 Kf01 = *(const bf16x8*)(kt + 32);         // nt=0, d 32..63
    bf16x8 Kf10 = *(const bf16x8*)(kt + 1024);       // nt=1, d 0..31
    bf16x8 Kf11 = *(const bf16x8*)(kt + 1056);       // nt=1, d 32..63
    bf16x8 Vf0 = *(const bf16x8*)(vp);               // d 0..15
    bf16x8 Vf1 = *(const bf16x8*)(vp + 32768);       // d 16..31
    bf16x8 Vf2 = *(const bf16x8*)(vp + 65536);       // d 32..47
    bf16x8 Vf3 = *(const bf16x8*)(vp + 98304);       // d 48..63
    // S^T = K·Q^T (lane c = q-col, rows = tokens)
    f32x4 S00 = {}, S01 = {}, S10 = {}, S11 = {};
    S00 = MFMA16(Kf00, Qf[0][0], S00); S00 = MFMA16(Kf01, Qf[0][1], S00);
    S01 = MFMA16(Kf10, Qf[0][0], S01); S01 = MFMA16(Kf11, Qf[0][1], S01);
    S10 = MFMA16(Kf00, Qf[1][0], S10); S10 = MFMA16(Kf01, Qf[1][1], S10);
    S11 = MFMA16(Kf10, Qf[1][0], S11); S11 = MFMA16(Kf11, Qf[1][1], S11);
    // P = exp2(S), packed so pa k-slots match the vtd token permutation
    bf16x8 pa0, pa1;
    {
      float e0 = EXP2(S00[0]), e1 = EXP2(S00[1]), e2 = EXP2(S00[2]), e3 = EXP2(S00[3]);
      float e4 = EXP2(S01[0]), e5 = EXP2(S01[1]), e6 = EXP2(S01[2]), e7 = EXP2(S01[3]);
      union { uint4 u; bf16x8 v; } cv;
      cv.u.x = pkbf(e0, e1); cv.u.y = pkbf(e2, e3);
      cv.u.z = pkbf(e4, e5); cv.u.w = pkbf(e6, e7);
      pa0 = cv.v;
    }
    {
      float e0 = EXP2(S10[0]), e1 = EXP2(S10[1]), e2 = EXP2(S10[2]), e3 = EXP2(S10[3]);
      float e4 = EXP2(S11[0]), e5 = EXP2(S11[1]), e6 = EXP2(S11[2]), e7 = EXP2(S11[3]);
      union { uint4 u; bf16x8 v; } cv;
      cv.u.x = pkbf(e0, e1); cv.u.y = pkbf(e2, e3);
      cv.u.z = pkbf(e4, e5); cv.u.w = pkbf(e6, e7);
      pa1 = cv.v;
    }
    Lacc[0] = MFMA16(pa0, vone, Lacc[0]);
    Lacc[1] = MFMA16(pa1, vone, Lacc[1]);
    O[0][0] = MFMA16(pa0, Vf0, O[0][0]);
    O[0][1] = MFMA16(pa0, Vf1, O[0][1]);
    O[0][2] = MFMA16(pa0, Vf2, O[0][2]);
    O[0][3] = MFMA16(pa0, Vf3, O[0][3]);
    O[1][0] = MFMA16(pa1, Vf0, O[1][0]);
    O[1][1] = MFMA16(pa1, Vf1, O[1][1]);
    O[1][2] = MFMA16(pa1, Vf2, O[1][2]);
    O[1][3] = MFMA16(pa1, Vf3, O[1][3]);
  }

  // ---- epilogue: combine the two waves' partials through LDS ----
  __syncthreads();
  if (w == 1) {
#pragma unroll
    for (int q2 = 0; q2 < 2; q2++) {
      if (c == 0)
        *(f32x4*)&CL[q2 * 16 + quad * 4] = Lacc[q2];
#pragma unroll
      for (int dt = 0; dt < 4; dt++)
#pragma unroll
        for (int j = 0; j < 4; j++)
          CmbO[(q2 * 16 + quad * 4 + j) * 64 + dt * 16 + c] = O[q2][dt][j];
    }
  }
  __syncthreads();
  if (w == 0) {
    int b_ = bh >> 4, h = bh & 15;
#pragma unroll
    for (int q2 = 0; q2 < 2; q2++) {
#pragma unroll
      for (int j = 0; j < 4; j++) {
        int qrow = q2 * 16 + quad * 4 + j;
        float ltot = Lacc[q2][j] + CL[qrow];
        float linv = 1.0f / ltot;
        int n = qt * 32 + qrow;
        u16* op = ot + (((size_t)b_ * 2048 + n) * 16 + h) * 64;
#pragma unroll
        for (int dt = 0; dt < 4; dt++) {
          float o = O[q2][dt][j] + CmbO[qrow * 64 + dt * 16 + c];
          op[dt * 16 + c] = f2bf(o * linv);
        }
      }
    }
  }
}

// ---------------- output projection GEMM (fp32 out), 64x128 tile ----------
__global__ __launch_bounds__(256) void gemm_out(
    const u16* __restrict__ Aot, const u16* __restrict__ wob,
    const float* __restrict__ bo, float* __restrict__ out)
{
  __shared__ u16 As[64 * 64];
  __shared__ u16 Bs[128 * 64];
  int tid = threadIdx.x, w = tid >> 6, lane = tid & 63;
  int bm = blockIdx.x, bn = blockIdx.y;
  int wm = w >> 1, wn = w & 1;
  f32x4 acc[2][4] = {};
  for (int k0 = 0; k0 < 1024; k0 += 64) {
#pragma unroll
    for (int i = 0; i < 2; i++) {
      int seg = i * 256 + tid;
      int row = seg >> 3, pseg = seg & 7;
      int lseg = pseg ^ (row & 7);
      gld16(Aot + (size_t)(bm * 64 + row) * 1024 + k0 + lseg * 8,
            &As[(i * 256 + tid - (tid & 7)) * 8 + (tid & 7) * 8]);
    }
#pragma unroll
    for (int i = 0; i < 4; i++) {
      int seg = i * 256 + tid;
      int row = seg >> 3, pseg = seg & 7;
      int lseg = pseg ^ (row & 7);
      gld16(wob + (size_t)(bn * 128 + row) * 1024 + k0 + lseg * 8,
            &Bs[(i * 256 + tid - (tid & 7)) * 8 + (tid & 7) * 8]);
    }
    __syncthreads();
#pragma unroll
    for (int ks = 0; ks < 2; ks++) {
      bf16x8 af[2], bfr[4];
#pragma unroll
      for (int mt = 0; mt < 2; mt++) {
        int row = wm * 32 + mt * 16 + (lane & 15);
        int cseg = (ks * 4 + (lane >> 4)) ^ (row & 7);
        af[mt] = *(const bf16x8*)&As[(row * 8 + cseg) * 8];
      }
#pragma unroll
      for (int nt = 0; nt < 4; nt++) {
        int row = wn * 64 + nt * 16 + (lane & 15);
        int cseg = (ks * 4 + (lane >> 4)) ^ (row & 7);
        bfr[nt] = *(const bf16x8*)&Bs[(row * 8 + cseg) * 8];
      }
#pragma unroll
      for (int mt = 0; mt < 2; mt++)
#pragma unroll
        for (int nt = 0; nt < 4; nt++)
          acc[mt][nt] = MFMA16(af[mt], bfr[nt], acc[mt][nt]);
    }
    __syncthreads();
  }
#pragma unroll
  for (int nt = 0; nt < 4; nt++) {
    int o = bn * 128 + wn * 64 + nt * 16 + (lane & 15);
    float bval = bo[o];
#pragma unroll
    for (int mt = 0; mt < 2; mt++)
#pragma unroll
      for (int j = 0; j < 4; j++) {
        int m = bm * 64 + wm * 32 + mt * 16 + (lane >> 4) * 4 + j;
        out[(size_t)m * 1024 + o] = acc[mt][nt][j] + bval;
      }
  }
}

extern "C" void kernel_launch(void* const* d_in, const int* in_sizes, int n_in,
                              void* d_out, int out_size, void* d_ws, size_t ws_size,
                              hipStream_t stream)
{
  const float* x  = (const float*)d_in[0];
  const float* qu = (const float*)d_in[1];
  const float* wq = (const float*)d_in[2];
  const float* bq = (const float*)d_in[3];
  const float* wk = (const float*)d_in[4];
  const float* bk = (const float*)d_in[5];
  const float* wv = (const float*)d_in[6];
  const float* bv = (const float*)d_in[7];
  const float* wo = (const float*)d_in[8];
  const float* bo = (const float*)d_in[9];
  float* out = (float*)d_out;
  char* ws = (char*)d_ws;
  u16* xb  = (u16*)(ws + (size_t)0);          // 8 MB
  u16* qub = (u16*)(ws + ((size_t)8  << 20)); // 8 MB
  u16* wqb = (u16*)(ws + ((size_t)16 << 20)); // 2 MB
  u16* wkb = (u16*)(ws + ((size_t)18 << 20)); // 2 MB
  u16* wvb = (u16*)(ws + ((size_t)20 << 20)); // 2 MB
  u16* wob = (u16*)(ws + ((size_t)22 << 20)); // 2 MB
  u16* qhd = (u16*)(ws + ((size_t)24 << 20)); // 8 MB  Q-scaled [B,H,N,D]
  u16* khd = (u16*)(ws + ((size_t)32 << 20)); // 8 MB  K [B,H,N,D]
  u16* vtd = (u16*)(ws + ((size_t)40 << 20)); // 8 MB  V^T permuted [B,H,D,N']
  u16* otd = (u16*)(ws + ((size_t)48 << 20)); // 8 MB  attn out [B,N,H,D]

  cast_all<<<12288, 256, 0, stream>>>(x, qu, wq, wk, wv, wo,
                                      xb, qub, wqb, wkb, wvb, wob);
  gemm_qkv<<<dim3(32, 8, 3), 256, 0, stream>>>(qub, xb, wqb, wkb, wvb,
                                               bq, bk, bv, qhd, khd, vtd);
  attn<<<dim3(32, 64), 128, 0, stream>>>(qhd, khd, vtd, otd);
  gemm_out<<<dim3(64, 8), 256, 0, stream>>>(otd, wob, bo, out);
}

// Round 6
// 208.182 us; speedup vs baseline: 2.0991x; 1.3231x over previous
//
#include <hip/hip_runtime.h>
#include <hip/hip_bf16.h>

typedef __attribute__((ext_vector_type(8))) short bf16x8;
typedef __attribute__((ext_vector_type(4))) float f32x4;
typedef unsigned short u16;
typedef unsigned int u32;

#define MFMA16(a,b,c) __builtin_amdgcn_mfma_f32_16x16x32_bf16((a),(b),(c),0,0,0)

#if defined(__has_builtin) && __has_builtin(__builtin_amdgcn_exp2f)
#define EXP2(x) __builtin_amdgcn_exp2f(x)
#else
#define EXP2(x) exp2f(x)
#endif

// softmax scale folded into Q at projection time: (1/32) * log2(e)
#define QSCALE 0.045084220027780106f

__device__ __forceinline__ u16 f2bf(float f) {
  union { float f; unsigned int u; } v; v.f = f;
  unsigned int r = v.u + 0x7FFFu + ((v.u >> 16) & 1u);   // RNE
  return (u16)(r >> 16);
}

__device__ __forceinline__ u32 pkbf(float a, float b) {
  union { __hip_bfloat162 h; u32 u; } cv;
  cv.h = __float22bfloat162_rn(make_float2(a, b));
  return cv.u;
}

// async global->LDS, 16B per lane; LDS dest = wave-uniform base + lane*16
__device__ __forceinline__ void gld16(const void* g, void* l) {
  __builtin_amdgcn_global_load_lds(
      (__attribute__((address_space(1))) void*)(g),
      (__attribute__((address_space(3))) void*)(l), 16, 0, 0);
}

// ---------------- cast fp32 -> bf16 (all inputs, one launch) ----------------
__global__ __launch_bounds__(256) void cast_all(
    const float* __restrict__ x, const float* __restrict__ qu,
    const float* __restrict__ wq, const float* __restrict__ wk,
    const float* __restrict__ wv, const float* __restrict__ wo,
    u16* __restrict__ xb, u16* __restrict__ qub,
    u16* __restrict__ wqb, u16* __restrict__ wkb,
    u16* __restrict__ wvb, u16* __restrict__ wob)
{
  int i = blockIdx.x * 256 + threadIdx.x;   // float4 index
  const float4* src; u16* dst; int off;
  if (i < 1048576)      { src = (const float4*)qu; dst = qub; off = i; }
  else if (i < 2097152) { src = (const float4*)x;  dst = xb;  off = i - 1048576; }
  else if (i < 2359296) { src = (const float4*)wq; dst = wqb; off = i - 2097152; }
  else if (i < 2621440) { src = (const float4*)wk; dst = wkb; off = i - 2359296; }
  else if (i < 2883584) { src = (const float4*)wv; dst = wvb; off = i - 2621440; }
  else                  { src = (const float4*)wo; dst = wob; off = i - 2883584; }
  float4 v = src[off];
  ushort4 r; r.x = f2bf(v.x); r.y = f2bf(v.y); r.z = f2bf(v.z); r.w = f2bf(v.w);
  ((ushort4*)dst)[off] = r;
}

// ---------------- fused QKV projection GEMM ----------------
// z=0: Q*(scale*log2e) -> [B,H,N,D]; z=1: K -> [B,H,N,D]  — computed as C^T
//      (swap MFMA operands) so each lane holds 4 consecutive channels ->
//      packed 8-B stores, no LDS transpose.
// z=2: V -> [B,H,D,N'] — normal orientation: lane j-values are 4 consecutive
//      permuted tokens (k' = (mt&2)*16 + quad*8 + (mt&1)*4 + j) -> packed
//      8-B stores directly into the transposed layout.
__global__ __launch_bounds__(256) void gemm_qkv(
    const u16* __restrict__ qub, const u16* __restrict__ xb,
    const u16* __restrict__ wqb, const u16* __restrict__ wkb, const u16* __restrict__ wvb,
    const float* __restrict__ bq, const float* __restrict__ bk, const float* __restrict__ bv,
    u16* __restrict__ qhd, u16* __restrict__ khd, u16* __restrict__ vtd)
{
  __shared__ u16 As[128 * 64];
  __shared__ u16 Bs[128 * 64];
  int tid = threadIdx.x, w = tid >> 6, lane = tid & 63;
  int c = lane & 15, quad = lane >> 4;
  int bm = blockIdx.x, bn = blockIdx.y, z = blockIdx.z;
  int wm = w >> 1, wn = w & 1;
  const u16* A = (z == 0) ? qub : xb;
  const u16* W = (z == 0) ? wqb : (z == 1) ? wkb : wvb;
  f32x4 acc[4][4] = {};
  for (int k0 = 0; k0 < 1024; k0 += 64) {
#pragma unroll
    for (int i = 0; i < 4; i++) {
      int seg = i * 256 + w * 64 + lane;          // physical 8-elem segment
      int row = seg >> 3, pseg = seg & 7;
      int lseg = pseg ^ (row & 7);                // logical k-segment (XOR swizzle)
      gld16(A + (size_t)(bm * 128 + row) * 1024 + k0 + lseg * 8,
            &As[(i * 256 + w * 64) * 8]);
      gld16(W + (size_t)(bn * 128 + row) * 1024 + k0 + lseg * 8,
            &Bs[(i * 256 + w * 64) * 8]);
    }
    __syncthreads();
#pragma unroll
    for (int ks = 0; ks < 2; ks++) {
      bf16x8 af[4], bfr[4];
#pragma unroll
      for (int mt = 0; mt < 4; mt++) {
        int row = wm * 64 + mt * 16 + c;
        int cseg = (ks * 4 + quad) ^ (row & 7);
        af[mt] = *(const bf16x8*)&As[(row * 8 + cseg) * 8];
      }
#pragma unroll
      for (int nt = 0; nt < 4; nt++) {
        int row = wn * 64 + nt * 16 + c;
        int cseg = (ks * 4 + quad) ^ (row & 7);
        bfr[nt] = *(const bf16x8*)&Bs[(row * 8 + cseg) * 8];
      }
      if (z < 2) {
        // C^T: rows = channels (W frags as A-operand), cols = tokens
#pragma unroll
        for (int ct = 0; ct < 4; ct++)
#pragma unroll
          for (int tt = 0; tt < 4; tt++)
            acc[ct][tt] = MFMA16(bfr[ct], af[tt], acc[ct][tt]);
      } else {
#pragma unroll
        for (int mt = 0; mt < 4; mt++)
#pragma unroll
          for (int nt = 0; nt < 4; nt++)
            acc[mt][nt] = MFMA16(af[mt], bfr[nt], acc[mt][nt]);
      }
    }
    __syncthreads();
  }
  if (z < 2) {
    const float* bias = (z == 0) ? bq : bk;
    u16* dst = (z == 0) ? qhd : khd;
    float sc = (z == 0) ? QSCALE : 1.0f;
    // per-lane bias for 4 consecutive channels per ct (16B-aligned)
    float4 bbs[4];
#pragma unroll
    for (int ct = 0; ct < 4; ct++) {
      float4 b4 = *(const float4*)&bias[bn * 128 + wn * 64 + ct * 16 + quad * 4];
      bbs[ct].x = b4.x * sc; bbs[ct].y = b4.y * sc;
      bbs[ct].z = b4.z * sc; bbs[ct].w = b4.w * sc;
    }
#pragma unroll
    for (int ct = 0; ct < 4; ct++) {
      int ch = bn * 128 + wn * 64 + ct * 16 + quad * 4;
      int h = ch >> 6, d0 = ch & 63;
#pragma unroll
      for (int tt = 0; tt < 4; tt++) {
        int tok = bm * 128 + wm * 64 + tt * 16 + c;
        int b = tok >> 11, n = tok & 2047;
        float v0 = fmaf(acc[ct][tt][0], sc, bbs[ct].x);
        float v1 = fmaf(acc[ct][tt][1], sc, bbs[ct].y);
        float v2 = fmaf(acc[ct][tt][2], sc, bbs[ct].z);
        float v3 = fmaf(acc[ct][tt][3], sc, bbs[ct].w);
        uint2 pk; pk.x = pkbf(v0, v1); pk.y = pkbf(v2, v3);
        *(uint2*)&dst[((size_t)(b * 16 + h) * 2048 + n) * 64 + d0] = pk;
      }
    }
  } else {
    float bval[4];
#pragma unroll
    for (int nt = 0; nt < 4; nt++)
      bval[nt] = bv[bn * 128 + wn * 64 + nt * 16 + c];
#pragma unroll
    for (int mt = 0; mt < 4; mt++) {
      int tokl = (mt & 2) * 16 + quad * 8 + (mt & 1) * 4;   // permuted, +j
      int tok = bm * 128 + wm * 64 + tokl;
      int b = tok >> 11, np = tok & 2047;
#pragma unroll
      for (int nt = 0; nt < 4; nt++) {
        int ch = bn * 128 + wn * 64 + nt * 16 + c;
        int h = ch >> 6, d = ch & 63;
        float v0 = acc[mt][nt][0] + bval[nt];
        float v1 = acc[mt][nt][1] + bval[nt];
        float v2 = acc[mt][nt][2] + bval[nt];
        float v3 = acc[mt][nt][3] + bval[nt];
        uint2 pk; pk.x = pkbf(v0, v1); pk.y = pkbf(v2, v3);
        *(uint2*)&vtd[((size_t)(b * 16 + h) * 64 + d) * 2048 + np] = pk;
      }
    }
  }
}

// ---------------- attention v11: v6 structure + counted vmcnt (T4) --------
// grid (32 bh, 32 qt): 1024 blocks of 128 threads (2 waves), 64-q tile,
// wave owns 32 q. Identical math/layout to v6 (R0 baseline, 56 us).
// ONLY the sync changed: per iter, 2 raw s_barriers + per-wave
// s_waitcnt vmcnt(8) instead of a draining __syncthreads().
//   iter t: [barrier_A] STAGE(t+1) [vmcnt(8)] [barrier_B] compute(t)
// vmcnt(8) after issuing STAGE(t+1) (8 gld16/wave) confirms own STAGE(t);
// barrier_B makes it mutual -> buf[t] safe to read. barrier_A separates
// both waves' compute(t-1) (reads of buf[(t+1)&1], completed via compiler
// lgkm waits before their MFMAs) from STAGE(t+1)'s overwrite of that buf.
// Prefetch stays in flight across the whole compute phase (never drains).
__global__ __launch_bounds__(128) void attn(
    const u16* __restrict__ qh, const u16* __restrict__ kh,
    const u16* __restrict__ vt, u16* __restrict__ ot)
{
  __shared__ u16 Kbuf[2][64 * 64];   // 8 KB each buf
  __shared__ u16 Vbuf[2][64 * 64];
  int tid = threadIdx.x, w = tid >> 6, lane = tid & 63;
  int c = lane & 15, quad = lane >> 4;
  int bh = blockIdx.x, qt = blockIdx.y;
  const u16* qp = qh + ((size_t)bh * 2048 + qt * 64 + w * 32) * 64;

  // Q B-frags in registers: B[k=d][n=q], lane c = q-col
  bf16x8 Qf[2][2];
#pragma unroll
  for (int qt2 = 0; qt2 < 2; qt2++)
#pragma unroll
    for (int ks = 0; ks < 2; ks++)
      Qf[qt2][ks] = *(const bf16x8*)(qp + (size_t)(qt2 * 16 + c) * 64 + ks * 32 + quad * 8);

  // hoisted lane-invariant LDS fragment offsets (elements)
  int off0 = c * 64 + ((quad) ^ (c & 7)) * 8;
  int off1 = c * 64 + ((4 + quad) ^ (c & 7)) * 8;

  // staging: wave w covers rows {c2*16 + w*8 + (lane>>3)}, c2 = 0..3
  int sr = lane >> 3;                 // 0..7
  int row0 = w * 8 + sr;              // 0..15 ; row0&7 == sr&7
  int sls = (lane & 7) ^ (sr & 7);    // XOR swizzle
  const u16* kg = kh + (size_t)bh * 2048 * 64 + row0 * 64 + sls * 8;
  const u16* vg = vt + (size_t)bh * 64 * 2048 + row0 * 2048 + sls * 8;

#define STAGE(B)                                                                \
  {                                                                             \
    gld16(kg,          &Kbuf[B][(w * 64) * 8]);                                 \
    gld16(kg + 1024,   &Kbuf[B][(128 + w * 64) * 8]);                           \
    gld16(kg + 2048,   &Kbuf[B][(256 + w * 64) * 8]);                           \
    gld16(kg + 3072,   &Kbuf[B][(384 + w * 64) * 8]);                           \
    gld16(vg,          &Vbuf[B][(w * 64) * 8]);                                 \
    gld16(vg + 32768,  &Vbuf[B][(128 + w * 64) * 8]);                           \
    gld16(vg + 65536,  &Vbuf[B][(256 + w * 64) * 8]);                           \
    gld16(vg + 98304,  &Vbuf[B][(384 + w * 64) * 8]);                           \
    kg += 4096; vg += 64;                                                       \
  }

#define SB __builtin_amdgcn_sched_barrier(0);
#define BARR  SB __builtin_amdgcn_s_barrier(); SB
// pipeline boundary: barrier_A, stage next tile, counted wait, barrier_B
#define PIPE(B)                                                                 \
  BARR                                                                          \
  STAGE(B)                                                                      \
  SB asm volatile("s_waitcnt vmcnt(8)" ::: "memory"); SB                        \
  BARR

  f32x4 O[2][4] = {};
  f32x4 Lacc[2] = {};
  bf16x8 vone;
#pragma unroll
  for (int j = 0; j < 8; j++) vone[j] = (short)0x3F80;   // bf16 1.0

#define COMPUTE(PH)                                                             \
  {                                                                             \
    const u16* Ks = Kbuf[PH];                                                   \
    const u16* Vs = Vbuf[PH];                                                   \
    bf16x8 Kf[4][2];                                                            \
    _Pragma("unroll") for (int nt = 0; nt < 4; nt++) {                          \
      Kf[nt][0] = *(const bf16x8*)&Ks[off0 + nt * 1024];                        \
      Kf[nt][1] = *(const bf16x8*)&Ks[off1 + nt * 1024];                        \
    }                                                                           \
    f32x4 S[2][4] = {};                                                         \
    __builtin_amdgcn_s_setprio(1);                                              \
    _Pragma("unroll") for (int qt2 = 0; qt2 < 2; qt2++)                         \
      _Pragma("unroll") for (int nt = 0; nt < 4; nt++) {                        \
        S[qt2][nt] = MFMA16(Kf[nt][0], Qf[qt2][0], S[qt2][nt]);                 \
        S[qt2][nt] = MFMA16(Kf[nt][1], Qf[qt2][1], S[qt2][nt]);                 \
      }                                                                         \
    __builtin_amdgcn_s_setprio(0);                                              \
    bf16x8 pa[2][2];                                                            \
    _Pragma("unroll") for (int qt2 = 0; qt2 < 2; qt2++)                         \
      _Pragma("unroll") for (int i = 0; i < 2; i++) {                           \
        float e0 = EXP2(S[qt2][2 * i][0]), e1 = EXP2(S[qt2][2 * i][1]);         \
        float e2 = EXP2(S[qt2][2 * i][2]), e3 = EXP2(S[qt2][2 * i][3]);         \
        float e4 = EXP2(S[qt2][2 * i + 1][0]), e5 = EXP2(S[qt2][2 * i + 1][1]); \
        float e6 = EXP2(S[qt2][2 * i + 1][2]), e7 = EXP2(S[qt2][2 * i + 1][3]); \
        union { uint4 u; bf16x8 v; } cv;                                        \
        cv.u.x = pkbf(e0, e1); cv.u.y = pkbf(e2, e3);                           \
        cv.u.z = pkbf(e4, e5); cv.u.w = pkbf(e6, e7);                           \
        pa[qt2][i] = cv.v;                                                      \
      }                                                                         \
    bf16x8 Vf[4][2];                                                            \
    _Pragma("unroll") for (int dt = 0; dt < 4; dt++) {                          \
      Vf[dt][0] = *(const bf16x8*)&Vs[off0 + dt * 1024];                        \
      Vf[dt][1] = *(const bf16x8*)&Vs[off1 + dt * 1024];                        \
    }                                                                           \
    __builtin_amdgcn_s_setprio(1);                                              \
    Lacc[0] = MFMA16(pa[0][0], vone, Lacc[0]);                                  \
    Lacc[0] = MFMA16(pa[0][1], vone, Lacc[0]);                                  \
    Lacc[1] = MFMA16(pa[1][0], vone, Lacc[1]);                                  \
    Lacc[1] = MFMA16(pa[1][1], vone, Lacc[1]);                                  \
    _Pragma("unroll") for (int qt2 = 0; qt2 < 2; qt2++)                         \
      _Pragma("unroll") for (int dt = 0; dt < 4; dt++) {                        \
        O[qt2][dt] = MFMA16(pa[qt2][0], Vf[dt][0], O[qt2][dt]);                 \
        O[qt2][dt] = MFMA16(pa[qt2][1], Vf[dt][1], O[qt2][dt]);                 \
      }                                                                         \
    __builtin_amdgcn_s_setprio(0);                                              \
  }

  // prologue: tile 0 in flight
  STAGE(0)
  // steady state: tiles 0..29 in pairs; each PIPE stages t+1 and waits t
  for (int kt2 = 0; kt2 < 15; kt2++) {
    PIPE(1) COMPUTE(0)
    PIPE(0) COMPUTE(1)
  }
  // t=30: stage tile 31, compute tile 30
  PIPE(1) COMPUTE(0)
  // t=31: no stage; drain the last 8 loads, compute tile 31
  BARR
  SB asm volatile("s_waitcnt vmcnt(0)" ::: "memory"); SB
  BARR
  COMPUTE(1)
#undef COMPUTE
#undef PIPE
#undef BARR
#undef SB
#undef STAGE

  // epilogue: Lacc[qt2][j] = row-sum for q = qt2*16 + quad*4 + j (all c equal)
  int b_ = bh >> 4, h = bh & 15;
#pragma unroll
  for (int qt2 = 0; qt2 < 2; qt2++) {
    f32x4 linv;
#pragma unroll
    for (int j = 0; j < 4; j++) linv[j] = 1.0f / Lacc[qt2][j];
#pragma unroll
    for (int j = 0; j < 4; j++) {
      int n = qt * 64 + w * 32 + qt2 * 16 + quad * 4 + j;
      u16* op = ot + (((size_t)b_ * 2048 + n) * 16 + h) * 64;
#pragma unroll
      for (int dt = 0; dt < 4; dt++)
        op[dt * 16 + c] = f2bf(O[qt2][dt][j] * linv[j]);
    }
  }
}

// ---------------- output projection GEMM (fp32 out), 64x128 tile ----------
__global__ __launch_bounds__(256) void gemm_out(
    const u16* __restrict__ Aot, const u16* __restrict__ wob,
    const float* __restrict__ bo, float* __restrict__ out)
{
  __shared__ u16 As[64 * 64];
  __shared__ u16 Bs[128 * 64];
  int tid = threadIdx.x, w = tid >> 6, lane = tid & 63;
  int bm = blockIdx.x, bn = blockIdx.y;
  int wm = w >> 1, wn = w & 1;
  f32x4 acc[2][4] = {};
  for (int k0 = 0; k0 < 1024; k0 += 64) {
#pragma unroll
    for (int i = 0; i < 2; i++) {
      int seg = i * 256 + tid;
      int row = seg >> 3, pseg = seg & 7;
      int lseg = pseg ^ (row & 7);
      gld16(Aot + (size_t)(bm * 64 + row) * 1024 + k0 + lseg * 8,
            &As[(i * 256 + tid - (tid & 7)) * 8 + (tid & 7) * 8]);
    }
#pragma unroll
    for (int i = 0; i < 4; i++) {
      int seg = i * 256 + tid;
      int row = seg >> 3, pseg = seg & 7;
      int lseg = pseg ^ (row & 7);
      gld16(wob + (size_t)(bn * 128 + row) * 1024 + k0 + lseg * 8,
            &Bs[(i * 256 + tid - (tid & 7)) * 8 + (tid & 7) * 8]);
    }
    __syncthreads();
#pragma unroll
    for (int ks = 0; ks < 2; ks++) {
      bf16x8 af[2], bfr[4];
#pragma unroll
      for (int mt = 0; mt < 2; mt++) {
        int row = wm * 32 + mt * 16 + (lane & 15);
        int cseg = (ks * 4 + (lane >> 4)) ^ (row & 7);
        af[mt] = *(const bf16x8*)&As[(row * 8 + cseg) * 8];
      }
#pragma unroll
      for (int nt = 0; nt < 4; nt++) {
        int row = wn * 64 + nt * 16 + (lane & 15);
        int cseg = (ks * 4 + (lane >> 4)) ^ (row & 7);
        bfr[nt] = *(const bf16x8*)&Bs[(row * 8 + cseg) * 8];
      }
#pragma unroll
      for (int mt = 0; mt < 2; mt++)
#pragma unroll
        for (int nt = 0; nt < 4; nt++)
          acc[mt][nt] = MFMA16(af[mt], bfr[nt], acc[mt][nt]);
    }
    __syncthreads();
  }
#pragma unroll
  for (int nt = 0; nt < 4; nt++) {
    int o = bn * 128 + wn * 64 + nt * 16 + (lane & 15);
    float bval = bo[o];
#pragma unroll
    for (int mt = 0; mt < 2; mt++)
#pragma unroll
      for (int j = 0; j < 4; j++) {
        int m = bm * 64 + wm * 32 + mt * 16 + (lane >> 4) * 4 + j;
        out[(size_t)m * 1024 + o] = acc[mt][nt][j] + bval;
      }
  }
}

extern "C" void kernel_launch(void* const* d_in, const int* in_sizes, int n_in,
                              void* d_out, int out_size, void* d_ws, size_t ws_size,
                              hipStream_t stream)
{
  const float* x  = (const float*)d_in[0];
  const float* qu = (const float*)d_in[1];
  const float* wq = (const float*)d_in[2];
  const float* bq = (const float*)d_in[3];
  const float* wk = (const float*)d_in[4];
  const float* bk = (const float*)d_in[5];
  const float* wv = (const float*)d_in[6];
  const float* bv = (const float*)d_in[7];
  const float* wo = (const float*)d_in[8];
  const float* bo = (const float*)d_in[9];
  float* out = (float*)d_out;
  char* ws = (char*)d_ws;
  u16* xb  = (u16*)(ws + (size_t)0);          // 8 MB
  u16* qub = (u16*)(ws + ((size_t)8  << 20)); // 8 MB
  u16* wqb = (u16*)(ws + ((size_t)16 << 20)); // 2 MB
  u16* wkb = (u16*)(ws + ((size_t)18 << 20)); // 2 MB
  u16* wvb = (u16*)(ws + ((size_t)20 << 20)); // 2 MB
  u16* wob = (u16*)(ws + ((size_t)22 << 20)); // 2 MB
  u16* qhd = (u16*)(ws + ((size_t)24 << 20)); // 8 MB  Q-scaled [B,H,N,D]
  u16* khd = (u16*)(ws + ((size_t)32 << 20)); // 8 MB  K [B,H,N,D]
  u16* vtd = (u16*)(ws + ((size_t)40 << 20)); // 8 MB  V^T permuted [B,H,D,N']
  u16* otd = (u16*)(ws + ((size_t)48 << 20)); // 8 MB  attn out [B,N,H,D]

  cast_all<<<12288, 256, 0, stream>>>(x, qu, wq, wk, wv, wo,
                                      xb, qub, wqb, wkb, wvb, wob);
  gemm_qkv<<<dim3(32, 8, 3), 256, 0, stream>>>(qub, xb, wqb, wkb, wvb,
                                               bq, bk, bv, qhd, khd, vtd);
  attn<<<dim3(32, 32), 128, 0, stream>>>(qhd, khd, vtd, otd);
  gemm_out<<<dim3(64, 8), 256, 0, stream>>>(otd, wob, bo, out);
}

// Round 7
// 201.367 us; speedup vs baseline: 2.1702x; 1.0338x over previous
//
#include <hip/hip_runtime.h>
#include <hip/hip_bf16.h>

typedef __attribute__((ext_vector_type(8))) short bf16x8;
typedef __attribute__((ext_vector_type(4))) float f32x4;
typedef unsigned short u16;
typedef unsigned int u32;

#define MFMA16(a,b,c) __builtin_amdgcn_mfma_f32_16x16x32_bf16((a),(b),(c),0,0,0)

#if defined(__has_builtin) && __has_builtin(__builtin_amdgcn_exp2f)
#define EXP2(x) __builtin_amdgcn_exp2f(x)
#else
#define EXP2(x) exp2f(x)
#endif

// softmax scale folded into Q at projection time: (1/32) * log2(e)
#define QSCALE 0.045084220027780106f

__device__ __forceinline__ u16 f2bf(float f) {
  union { float f; unsigned int u; } v; v.f = f;
  unsigned int r = v.u + 0x7FFFu + ((v.u >> 16) & 1u);   // RNE
  return (u16)(r >> 16);
}

__device__ __forceinline__ u32 pkbf(float a, float b) {
  union { __hip_bfloat162 h; u32 u; } cv;
  cv.h = __float22bfloat162_rn(make_float2(a, b));
  return cv.u;
}

// async global->LDS, 16B per lane; LDS dest = wave-uniform base + lane*16
__device__ __forceinline__ void gld16(const void* g, void* l) {
  __builtin_amdgcn_global_load_lds(
      (__attribute__((address_space(1))) void*)(g),
      (__attribute__((address_space(3))) void*)(l), 16, 0, 0);
}

// ---------------- cast fp32 -> bf16 (all inputs, one launch) ----------------
__global__ __launch_bounds__(256) void cast_all(
    const float* __restrict__ x, const float* __restrict__ qu,
    const float* __restrict__ wq, const float* __restrict__ wk,
    const float* __restrict__ wv, const float* __restrict__ wo,
    u16* __restrict__ xb, u16* __restrict__ qub,
    u16* __restrict__ wqb, u16* __restrict__ wkb,
    u16* __restrict__ wvb, u16* __restrict__ wob)
{
  int i = blockIdx.x * 256 + threadIdx.x;   // float4 index
  const float4* src; u16* dst; int off;
  if (i < 1048576)      { src = (const float4*)qu; dst = qub; off = i; }
  else if (i < 2097152) { src = (const float4*)x;  dst = xb;  off = i - 1048576; }
  else if (i < 2359296) { src = (const float4*)wq; dst = wqb; off = i - 2097152; }
  else if (i < 2621440) { src = (const float4*)wk; dst = wkb; off = i - 2359296; }
  else if (i < 2883584) { src = (const float4*)wv; dst = wvb; off = i - 2621440; }
  else                  { src = (const float4*)wo; dst = wob; off = i - 2883584; }
  float4 v = src[off];
  ushort4 r; r.x = f2bf(v.x); r.y = f2bf(v.y); r.z = f2bf(v.z); r.w = f2bf(v.w);
  ((ushort4*)dst)[off] = r;
}

// ---------------- fused QKV projection GEMM ----------------
// z=0: Q*(scale*log2e) -> [B,H,N,D]; z=1: K -> [B,H,N,D]  — computed as C^T
//      (swap MFMA operands) so each lane holds 4 consecutive channels ->
//      packed 8-B stores, no LDS transpose.
// z=2: V -> [B,H,D,N'] — normal orientation: lane j-values are 4 consecutive
//      permuted tokens (k' = (mt&2)*16 + quad*8 + (mt&1)*4 + j) -> packed
//      8-B stores directly into the transposed layout.
__global__ __launch_bounds__(256) void gemm_qkv(
    const u16* __restrict__ qub, const u16* __restrict__ xb,
    const u16* __restrict__ wqb, const u16* __restrict__ wkb, const u16* __restrict__ wvb,
    const float* __restrict__ bq, const float* __restrict__ bk, const float* __restrict__ bv,
    u16* __restrict__ qhd, u16* __restrict__ khd, u16* __restrict__ vtd)
{
  __shared__ u16 As[128 * 64];
  __shared__ u16 Bs[128 * 64];
  int tid = threadIdx.x, w = tid >> 6, lane = tid & 63;
  int c = lane & 15, quad = lane >> 4;
  int bm = blockIdx.x, bn = blockIdx.y, z = blockIdx.z;
  int wm = w >> 1, wn = w & 1;
  const u16* A = (z == 0) ? qub : xb;
  const u16* W = (z == 0) ? wqb : (z == 1) ? wkb : wvb;
  f32x4 acc[4][4] = {};
  for (int k0 = 0; k0 < 1024; k0 += 64) {
#pragma unroll
    for (int i = 0; i < 4; i++) {
      int seg = i * 256 + w * 64 + lane;          // physical 8-elem segment
      int row = seg >> 3, pseg = seg & 7;
      int lseg = pseg ^ (row & 7);                // logical k-segment (XOR swizzle)
      gld16(A + (size_t)(bm * 128 + row) * 1024 + k0 + lseg * 8,
            &As[(i * 256 + w * 64) * 8]);
      gld16(W + (size_t)(bn * 128 + row) * 1024 + k0 + lseg * 8,
            &Bs[(i * 256 + w * 64) * 8]);
    }
    __syncthreads();
#pragma unroll
    for (int ks = 0; ks < 2; ks++) {
      bf16x8 af[4], bfr[4];
#pragma unroll
      for (int mt = 0; mt < 4; mt++) {
        int row = wm * 64 + mt * 16 + c;
        int cseg = (ks * 4 + quad) ^ (row & 7);
        af[mt] = *(const bf16x8*)&As[(row * 8 + cseg) * 8];
      }
#pragma unroll
      for (int nt = 0; nt < 4; nt++) {
        int row = wn * 64 + nt * 16 + c;
        int cseg = (ks * 4 + quad) ^ (row & 7);
        bfr[nt] = *(const bf16x8*)&Bs[(row * 8 + cseg) * 8];
      }
      if (z < 2) {
        // C^T: rows = channels (W frags as A-operand), cols = tokens
#pragma unroll
        for (int ct = 0; ct < 4; ct++)
#pragma unroll
          for (int tt = 0; tt < 4; tt++)
            acc[ct][tt] = MFMA16(bfr[ct], af[tt], acc[ct][tt]);
      } else {
#pragma unroll
        for (int mt = 0; mt < 4; mt++)
#pragma unroll
          for (int nt = 0; nt < 4; nt++)
            acc[mt][nt] = MFMA16(af[mt], bfr[nt], acc[mt][nt]);
      }
    }
    __syncthreads();
  }
  if (z < 2) {
    const float* bias = (z == 0) ? bq : bk;
    u16* dst = (z == 0) ? qhd : khd;
    float sc = (z == 0) ? QSCALE : 1.0f;
    // per-lane bias for 4 consecutive channels per ct (16B-aligned)
    float4 bbs[4];
#pragma unroll
    for (int ct = 0; ct < 4; ct++) {
      float4 b4 = *(const float4*)&bias[bn * 128 + wn * 64 + ct * 16 + quad * 4];
      bbs[ct].x = b4.x * sc; bbs[ct].y = b4.y * sc;
      bbs[ct].z = b4.z * sc; bbs[ct].w = b4.w * sc;
    }
#pragma unroll
    for (int ct = 0; ct < 4; ct++) {
      int ch = bn * 128 + wn * 64 + ct * 16 + quad * 4;
      int h = ch >> 6, d0 = ch & 63;
#pragma unroll
      for (int tt = 0; tt < 4; tt++) {
        int tok = bm * 128 + wm * 64 + tt * 16 + c;
        int b = tok >> 11, n = tok & 2047;
        float v0 = fmaf(acc[ct][tt][0], sc, bbs[ct].x);
        float v1 = fmaf(acc[ct][tt][1], sc, bbs[ct].y);
        float v2 = fmaf(acc[ct][tt][2], sc, bbs[ct].z);
        float v3 = fmaf(acc[ct][tt][3], sc, bbs[ct].w);
        uint2 pk; pk.x = pkbf(v0, v1); pk.y = pkbf(v2, v3);
        *(uint2*)&dst[((size_t)(b * 16 + h) * 2048 + n) * 64 + d0] = pk;
      }
    }
  } else {
    float bval[4];
#pragma unroll
    for (int nt = 0; nt < 4; nt++)
      bval[nt] = bv[bn * 128 + wn * 64 + nt * 16 + c];
#pragma unroll
    for (int mt = 0; mt < 4; mt++) {
      int tokl = (mt & 2) * 16 + quad * 8 + (mt & 1) * 4;   // permuted, +j
      int tok = bm * 128 + wm * 64 + tokl;
      int b = tok >> 11, np = tok & 2047;
#pragma unroll
      for (int nt = 0; nt < 4; nt++) {
        int ch = bn * 128 + wn * 64 + nt * 16 + c;
        int h = ch >> 6, d = ch & 63;
        float v0 = acc[mt][nt][0] + bval[nt];
        float v1 = acc[mt][nt][1] + bval[nt];
        float v2 = acc[mt][nt][2] + bval[nt];
        float v3 = acc[mt][nt][3] + bval[nt];
        uint2 pk; pk.x = pkbf(v0, v1); pk.y = pkbf(v2, v3);
        *(uint2*)&vtd[((size_t)(b * 16 + h) * 64 + d) * 2048 + np] = pk;
      }
    }
  }
}

// ---------------- attention v12: token-split waves, private LDS dbuf ------
// grid (32 bh, 32 qt), block = 128 thr (2 waves). Block owns a 64-q tile;
// BOTH waves compute all 64 q, but wave w sweeps only tokens
// [w*1024, w*1024+1024) in 32 tiles of 32, staging K (4KB) + V (4KB) into
// its PRIVATE double-buffer. Per wave-iter: 2048 scores from 8KB LDS read +
// 8KB stage = 16KB (v6: 24KB for same scores) -> per-CU LDS demand
// 192->128 KB/iter. Waves independent in sweep (per-wave counted vmcnt, no
// barriers); partials combined in LDS at epilogue (v9-verified pattern).
// VGPR ~220; __launch_bounds__(128,2) caps at 256 (no v9 spill cliff).
__global__ __launch_bounds__(128, 2) void attn(
    const u16* __restrict__ qh, const u16* __restrict__ kh,
    const u16* __restrict__ vt, u16* __restrict__ ot)
{
  __shared__ u16 KL[2][2][32 * 64];   // [wave][buf] K tile [32 tok][64 d], 4 KB
  __shared__ u16 VL[2][2][64 * 32];   // [wave][buf] V tile [64 d][32 tok'], 4 KB
  __shared__ float CL[64];            // wave-1 L partials
  int tid = threadIdx.x, w = tid >> 6, lane = tid & 63;
  int c = lane & 15, quad = lane >> 4;
  int bh = blockIdx.x, qt = blockIdx.y;

  // Q B-frags in registers: 64 q shared by both waves
  const u16* qp = qh + ((size_t)bh * 2048 + qt * 64) * 64;
  bf16x8 Qf[4][2];
#pragma unroll
  for (int q2 = 0; q2 < 4; q2++)
#pragma unroll
    for (int ks = 0; ks < 2; ks++)
      Qf[q2][ks] = *(const bf16x8*)(qp + (size_t)(q2 * 16 + c) * 64 + ks * 32 + quad * 8);

  // K staging: 4 loads; load i covers token-row i*8+(lane>>3), seg (lane&7)^(row&7)
  int kro = lane >> 3;                    // 0..7
  int ksw = ((lane & 7) ^ (kro & 7)) * 8;
  const u16* kg = kh + (size_t)bh * 131072 + (size_t)w * 65536 + kro * 64 + ksw;
  // V staging: 4 loads; load i covers d-row i*16+(lane>>2), seg (lane&3)^(row&3)
  int vro = lane >> 2;                    // 0..15
  int vsw = ((lane & 3) ^ (vro & 3)) * 8;
  const u16* vg = vt + (size_t)bh * 131072 + (size_t)vro * 2048 + w * 1024 + vsw;

  // fragment read offsets (swizzled)
  int off0 = c * 64 + ((quad) ^ (c & 7)) * 8;        // K ks=0 (d 0..31)
  int off1 = c * 64 + ((4 + quad) ^ (c & 7)) * 8;    // K ks=1 (d 32..63)
  int offV = c * 32 + ((quad ^ (c & 3)) & 3) * 8;    // V (+ dt*512)

#define STAGE(B)                                                                \
  {                                                                             \
    gld16(kg,          &KL[w][B][0]);                                           \
    gld16(kg + 512,    &KL[w][B][512]);                                         \
    gld16(kg + 1024,   &KL[w][B][1024]);                                        \
    gld16(kg + 1536,   &KL[w][B][1536]);                                        \
    gld16(vg,          &VL[w][B][0]);                                           \
    gld16(vg + 32768,  &VL[w][B][512]);                                         \
    gld16(vg + 65536,  &VL[w][B][1024]);                                        \
    gld16(vg + 98304,  &VL[w][B][1536]);                                        \
    kg += 2048; vg += 32;                                                       \
  }

  f32x4 O[4][4] = {};
  f32x4 Lacc[4] = {};
  bf16x8 vone;
#pragma unroll
  for (int j = 0; j < 8; j++) vone[j] = (short)0x3F80;   // bf16 1.0

  // per iter: [lgkm(0)] protect buf about to be overwritten; stage t+1;
  // counted vmcnt(8) -> tile t's 8 loads complete; compute tile t.
#define ITER(PH, PREF)                                                          \
  {                                                                             \
    asm volatile("s_waitcnt lgkmcnt(0)" ::: "memory");                          \
    __builtin_amdgcn_sched_barrier(0);                                          \
    if (PREF) STAGE(PH ^ 1)                                                     \
    if (PREF) { asm volatile("s_waitcnt vmcnt(8)" ::: "memory"); }              \
    else      { asm volatile("s_waitcnt vmcnt(0)" ::: "memory"); }              \
    __builtin_amdgcn_sched_barrier(0);                                          \
    const u16* Ks = KL[w][PH];                                                  \
    const u16* Vs = VL[w][PH];                                                  \
    bf16x8 Kf[2][2];                                                            \
    Kf[0][0] = *(const bf16x8*)&Ks[off0];                                       \
    Kf[0][1] = *(const bf16x8*)&Ks[off1];                                       \
    Kf[1][0] = *(const bf16x8*)&Ks[off0 + 1024];                                \
    Kf[1][1] = *(const bf16x8*)&Ks[off1 + 1024];                                \
    f32x4 S[4][2] = {};                                                         \
    _Pragma("unroll") for (int q2 = 0; q2 < 4; q2++)                            \
      _Pragma("unroll") for (int nt = 0; nt < 2; nt++) {                        \
        S[q2][nt] = MFMA16(Kf[nt][0], Qf[q2][0], S[q2][nt]);                    \
        S[q2][nt] = MFMA16(Kf[nt][1], Qf[q2][1], S[q2][nt]);                    \
      }                                                                         \
    bf16x8 pa[4];                                                               \
    _Pragma("unroll") for (int q2 = 0; q2 < 4; q2++) {                          \
      float e0 = EXP2(S[q2][0][0]), e1 = EXP2(S[q2][0][1]);                     \
      float e2 = EXP2(S[q2][0][2]), e3 = EXP2(S[q2][0][3]);                     \
      float e4 = EXP2(S[q2][1][0]), e5 = EXP2(S[q2][1][1]);                     \
      float e6 = EXP2(S[q2][1][2]), e7 = EXP2(S[q2][1][3]);                     \
      union { uint4 u; bf16x8 v; } cv;                                          \
      cv.u.x = pkbf(e0, e1); cv.u.y = pkbf(e2, e3);                             \
      cv.u.z = pkbf(e4, e5); cv.u.w = pkbf(e6, e7);                             \
      pa[q2] = cv.v;                                                            \
    }                                                                           \
    bf16x8 Vf[4];                                                               \
    Vf[0] = *(const bf16x8*)&Vs[offV];                                          \
    Vf[1] = *(const bf16x8*)&Vs[offV + 512];                                    \
    Vf[2] = *(const bf16x8*)&Vs[offV + 1024];                                   \
    Vf[3] = *(const bf16x8*)&Vs[offV + 1536];                                   \
    Lacc[0] = MFMA16(pa[0], vone, Lacc[0]);                                     \
    Lacc[1] = MFMA16(pa[1], vone, Lacc[1]);                                     \
    Lacc[2] = MFMA16(pa[2], vone, Lacc[2]);                                     \
    Lacc[3] = MFMA16(pa[3], vone, Lacc[3]);                                     \
    _Pragma("unroll") for (int q2 = 0; q2 < 4; q2++)                            \
      _Pragma("unroll") for (int dt = 0; dt < 4; dt++)                          \
        O[q2][dt] = MFMA16(pa[q2], Vf[dt], O[q2][dt]);                          \
  }

  // prologue: tile 0 in flight
  STAGE(0)
  // 32 iters: pairs with prefetch, then last tile without
  for (int t2 = 0; t2 < 15; t2++) {
    ITER(0, 1)
    ITER(1, 1)
  }
  ITER(0, 1)
  ITER(1, 0)
#undef ITER
#undef STAGE

  // ---- epilogue: combine the two waves' partials through LDS ----
  __syncthreads();
  float* CmbO = (float*)&KL[0][0][0];   // 16 KB: [64 q][64 d] f32 (wave-1)
  if (w == 1) {
#pragma unroll
    for (int q2 = 0; q2 < 4; q2++) {
      if (c == 0)
        *(f32x4*)&CL[q2 * 16 + quad * 4] = Lacc[q2];
#pragma unroll
      for (int dt = 0; dt < 4; dt++)
#pragma unroll
        for (int j = 0; j < 4; j++)
          CmbO[(q2 * 16 + quad * 4 + j) * 64 + dt * 16 + c] = O[q2][dt][j];
    }
  }
  __syncthreads();
  if (w == 0) {
    int b_ = bh >> 4, h = bh & 15;
#pragma unroll
    for (int q2 = 0; q2 < 4; q2++) {
#pragma unroll
      for (int j = 0; j < 4; j++) {
        int qrow = q2 * 16 + quad * 4 + j;
        float ltot = Lacc[q2][j] + CL[qrow];
        float linv = 1.0f / ltot;
        int n = qt * 64 + qrow;
        u16* op = ot + (((size_t)b_ * 2048 + n) * 16 + h) * 64;
#pragma unroll
        for (int dt = 0; dt < 4; dt++) {
          float o = O[q2][dt][j] + CmbO[qrow * 64 + dt * 16 + c];
          op[dt * 16 + c] = f2bf(o * linv);
        }
      }
    }
  }
}

// ---------------- output projection GEMM (fp32 out), 64x128 tile ----------
__global__ __launch_bounds__(256) void gemm_out(
    const u16* __restrict__ Aot, const u16* __restrict__ wob,
    const float* __restrict__ bo, float* __restrict__ out)
{
  __shared__ u16 As[64 * 64];
  __shared__ u16 Bs[128 * 64];
  int tid = threadIdx.x, w = tid >> 6, lane = tid & 63;
  int bm = blockIdx.x, bn = blockIdx.y;
  int wm = w >> 1, wn = w & 1;
  f32x4 acc[2][4] = {};
  for (int k0 = 0; k0 < 1024; k0 += 64) {
#pragma unroll
    for (int i = 0; i < 2; i++) {
      int seg = i * 256 + tid;
      int row = seg >> 3, pseg = seg & 7;
      int lseg = pseg ^ (row & 7);
      gld16(Aot + (size_t)(bm * 64 + row) * 1024 + k0 + lseg * 8,
            &As[(i * 256 + tid - (tid & 7)) * 8 + (tid & 7) * 8]);
    }
#pragma unroll
    for (int i = 0; i < 4; i++) {
      int seg = i * 256 + tid;
      int row = seg >> 3, pseg = seg & 7;
      int lseg = pseg ^ (row & 7);
      gld16(wob + (size_t)(bn * 128 + row) * 1024 + k0 + lseg * 8,
            &Bs[(i * 256 + tid - (tid & 7)) * 8 + (tid & 7) * 8]);
    }
    __syncthreads();
#pragma unroll
    for (int ks = 0; ks < 2; ks++) {
      bf16x8 af[2], bfr[4];
#pragma unroll
      for (int mt = 0; mt < 2; mt++) {
        int row = wm * 32 + mt * 16 + (lane & 15);
        int cseg = (ks * 4 + (lane >> 4)) ^ (row & 7);
        af[mt] = *(const bf16x8*)&As[(row * 8 + cseg) * 8];
      }
#pragma unroll
      for (int nt = 0; nt < 4; nt++) {
        int row = wn * 64 + nt * 16 + (lane & 15);
        int cseg = (ks * 4 + (lane >> 4)) ^ (row & 7);
        bfr[nt] = *(const bf16x8*)&Bs[(row * 8 + cseg) * 8];
      }
#pragma unroll
      for (int mt = 0; mt < 2; mt++)
#pragma unroll
        for (int nt = 0; nt < 4; nt++)
          acc[mt][nt] = MFMA16(af[mt], bfr[nt], acc[mt][nt]);
    }
    __syncthreads();
  }
#pragma unroll
  for (int nt = 0; nt < 4; nt++) {
    int o = bn * 128 + wn * 64 + nt * 16 + (lane & 15);
    float bval = bo[o];
#pragma unroll
    for (int mt = 0; mt < 2; mt++)
#pragma unroll
      for (int j = 0; j < 4; j++) {
        int m = bm * 64 + wm * 32 + mt * 16 + (lane >> 4) * 4 + j;
        out[(size_t)m * 1024 + o] = acc[mt][nt][j] + bval;
      }
  }
}

extern "C" void kernel_launch(void* const* d_in, const int* in_sizes, int n_in,
                              void* d_out, int out_size, void* d_ws, size_t ws_size,
                              hipStream_t stream)
{
  const float* x  = (const float*)d_in[0];
  const float* qu = (const float*)d_in[1];
  const float* wq = (const float*)d_in[2];
  const float* bq = (const float*)d_in[3];
  const float* wk = (const float*)d_in[4];
  const float* bk = (const float*)d_in[5];
  const float* wv = (const float*)d_in[6];
  const float* bv = (const float*)d_in[7];
  const float* wo = (const float*)d_in[8];
  const float* bo = (const float*)d_in[9];
  float* out = (float*)d_out;
  char* ws = (char*)d_ws;
  u16* xb  = (u16*)(ws + (size_t)0);          // 8 MB
  u16* qub = (u16*)(ws + ((size_t)8  << 20)); // 8 MB
  u16* wqb = (u16*)(ws + ((size_t)16 << 20)); // 2 MB
  u16* wkb = (u16*)(ws + ((size_t)18 << 20)); // 2 MB
  u16* wvb = (u16*)(ws + ((size_t)20 << 20)); // 2 MB
  u16* wob = (u16*)(ws + ((size_t)22 << 20)); // 2 MB
  u16* qhd = (u16*)(ws + ((size_t)24 << 20)); // 8 MB  Q-scaled [B,H,N,D]
  u16* khd = (u16*)(ws + ((size_t)32 << 20)); // 8 MB  K [B,H,N,D]
  u16* vtd = (u16*)(ws + ((size_t)40 << 20)); // 8 MB  V^T permuted [B,H,D,N']
  u16* otd = (u16*)(ws + ((size_t)48 << 20)); // 8 MB  attn out [B,N,H,D]

  cast_all<<<12288, 256, 0, stream>>>(x, qu, wq, wk, wv, wo,
                                      xb, qub, wqb, wkb, wvb, wob);
  gemm_qkv<<<dim3(32, 8, 3), 256, 0, stream>>>(qub, xb, wqb, wkb, wvb,
                                               bq, bk, bv, qhd, khd, vtd);
  attn<<<dim3(32, 32), 128, 0, stream>>>(qhd, khd, vtd, otd);
  gemm_out<<<dim3(64, 8), 256, 0, stream>>>(otd, wob, bo, out);
}